// Round 10
// baseline (1619.319 us; speedup 1.0000x reference)
//
#include <hip/hip_runtime.h>
#include <hip/hip_cooperative_groups.h>
#include <math.h>

namespace cg = cooperative_groups;

#define NN 40000
#define NE 640000
#define DD 128
#define NL 3
#define SCAN_NBLK ((NN + 255) / 256)        // 157
#define NB_CONV ((NE + 255) / 256)          // 2500
#define NWG (NL * 4 * DD * DD / 8)          // 24576 weight granules
#define NEG_LOG2E -1.4426950408889634f
#define GB 1024                             // mega-kernel persistent blocks
#define GSTRIDE (GB * 256)

typedef short s16x8 __attribute__((ext_vector_type(8)));
typedef float f32x4 __attribute__((ext_vector_type(4)));
typedef float f32x2 __attribute__((ext_vector_type(2)));
typedef unsigned int u32x2 __attribute__((ext_vector_type(2)));
typedef unsigned short ushort_t;

// bf16 <-> f32 via bit ops (RNE)
__device__ __forceinline__ ushort_t f2bf(float f) {
    unsigned int u = __float_as_uint(f);
    u = (u + 0x7FFFu + ((u >> 16) & 1u)) >> 16;
    return (ushort_t)u;
}

// ---------------------------------------------------------------------------
// Shared phase bodies (used by both the cooperative megakernel and fallback)
// ---------------------------------------------------------------------------
__device__ __forceinline__ bool detect64(const int* __restrict__ ei) {
    bool is64 = true;
    for (int k2 = 0; k2 < 32; ++k2)
        if (ei[2 * k2 + 1] != 0) { is64 = false; break; }
    return is64;
}

__device__ __forceinline__ void conv_edge(int e, bool is64, const int* __restrict__ ei,
                                          int* __restrict__ srcs, int* __restrict__ dsts,
                                          int* __restrict__ count) {
    int s, d;
    if (is64) {
        s = ei[2 * e];
        d = ei[2 * (NE + e)];
    } else {
        s = ei[e];
        d = ei[NE + e];
    }
    srcs[e] = s;
    dsts[e] = d;
    atomicAdd(&count[d], 1);
}

__device__ __forceinline__ void cvt_w_gran(int g, const float* __restrict__ Wk,
                                           const float* __restrict__ Wq,
                                           const float* __restrict__ Wv,
                                           const float* __restrict__ Ws,
                                           ushort_t* __restrict__ wall) {
    size_t flat = (size_t)g * 8;
    int l = (int)(flat / (4 * DD * DD));
    int r = (int)(flat % (4 * DD * DD));
    int m = r / (DD * DD);
    int o = r % (DD * DD);
    const float* src;
    switch (m) {
        case 0: src = Wk; break;
        case 1: src = Wq; break;
        case 2: src = Wv; break;
        default: src = Ws; break;
    }
    const float* p = src + (size_t)l * DD * DD + o;
    s16x8 ov;
#pragma unroll
    for (int j = 0; j < 8; ++j) ov[j] = (short)f2bf(p[j]);
    *(s16x8*)&wall[flat] = ov;
}

// One 64-row x 128-col 4-way MFMA GEMM tile. Outputs:
//  ks[node][256]:  element 2d = k'_d = -log2e*(k_d+bk_d), 2d+1 = s_d  (NT dwords)
//  gat[node][256]: element 2d = q'_d = -log2e*(q_d+bq_d), 2d+1 = v_d  (hot table)
__device__ __forceinline__ void gemm_tile(
    int tile, int l, const float* __restrict__ xf, const ushort_t* __restrict__ xb,
    const ushort_t* __restrict__ wall,
    const float* __restrict__ bk, const float* __restrict__ bq,
    const float* __restrict__ bv,
    ushort_t* __restrict__ ks, ushort_t* __restrict__ gat, ushort_t* wlds) {
    const int t = threadIdx.x;
    const int w = t >> 6;
    const int lane = t & 63;
    const int row0 = tile * 64;

    const int arow = row0 + w * 16 + (lane & 15);
    s16x8 afrag[4];
    if (xf) {
        const float* apf = xf + (size_t)arow * DD + ((lane >> 4) << 3);
#pragma unroll
        for (int kb = 0; kb < 4; ++kb) {
            f32x4 lo = *(const f32x4*)(apf + kb * 32);
            f32x4 hi = *(const f32x4*)(apf + kb * 32 + 4);
#pragma unroll
            for (int j = 0; j < 4; ++j) {
                afrag[kb][j] = (short)f2bf(lo[j]);
                afrag[kb][j + 4] = (short)f2bf(hi[j]);
            }
        }
    } else {
        const ushort_t* ap = xb + (size_t)arow * DD + ((lane >> 4) << 3);
#pragma unroll
        for (int kb = 0; kb < 4; ++kb) afrag[kb] = *(const s16x8*)(ap + kb * 32);
    }

    const int dlow = lane & 15;
    const int dbase = dlow * 256;
    const int swz = (lane & 7) << 4;
    const int g16 = (lane >> 4) << 4;

    unsigned qs_[8][2];   // q' bf16 pairs, m==1 -> m==2
    unsigned ksr[8][2];   // k' bf16 pairs, m==0 -> m==3

    for (int m = 0; m < 4; ++m) {
        if (m) __syncthreads();
        const ushort_t* wsrc = wall + (((size_t)l * 4 + m) << 14);
#pragma unroll
        for (int p = 0; p < 8; ++p) {
            int g = p * 256 + t;
            int d = g >> 4;
            int s = g & 15;
            int byteoff = d * 256 + ((s * 16) ^ ((d & 7) << 4));
            *(s16x8*)((char*)wlds + byteoff) = *(const s16x8*)(wsrc + (size_t)g * 8);
        }
        __syncthreads();

        f32x4 acc[8];
#pragma unroll
        for (int ct = 0; ct < 8; ++ct) acc[ct] = (f32x4){0.f, 0.f, 0.f, 0.f};

#pragma unroll
        for (int kb = 0; kb < 4; ++kb) {
#pragma unroll
            for (int ct = 0; ct < 8; ++ct) {
                s16x8 bfrag = *(const s16x8*)((char*)wlds + ct * 4096 + dbase +
                                              ((kb * 64 + g16) ^ swz));
                acc[ct] = __builtin_amdgcn_mfma_f32_16x16x32_bf16(afrag[kb], bfrag,
                                                                  acc[ct], 0, 0, 0);
            }
        }

        const int rbase = row0 + w * 16 + ((lane >> 4) << 2);
#pragma unroll
        for (int ct = 0; ct < 8; ++ct) {
            int c0 = ct * 16 + dlow;
            if (m == 0) {
                float bval = bk[l * DD + c0];
                ksr[ct][0] = (unsigned)f2bf((acc[ct][0] + bval) * NEG_LOG2E) |
                             ((unsigned)f2bf((acc[ct][1] + bval) * NEG_LOG2E) << 16);
                ksr[ct][1] = (unsigned)f2bf((acc[ct][2] + bval) * NEG_LOG2E) |
                             ((unsigned)f2bf((acc[ct][3] + bval) * NEG_LOG2E) << 16);
            } else if (m == 1) {
                float bval = bq[l * DD + c0];
                qs_[ct][0] = (unsigned)f2bf((acc[ct][0] + bval) * NEG_LOG2E) |
                             ((unsigned)f2bf((acc[ct][1] + bval) * NEG_LOG2E) << 16);
                qs_[ct][1] = (unsigned)f2bf((acc[ct][2] + bval) * NEG_LOG2E) |
                             ((unsigned)f2bf((acc[ct][3] + bval) * NEG_LOG2E) << 16);
            } else if (m == 2) {
                float bval = bv[l * DD + c0];
#pragma unroll
                for (int j = 0; j < 4; ++j) {
                    unsigned q16 = (qs_[ct][j >> 1] >> ((j & 1) * 16)) & 0xFFFFu;
                    unsigned val = q16 | ((unsigned)f2bf(acc[ct][j] + bval) << 16);
                    *(unsigned*)&gat[(size_t)(rbase + j) * 256 + 2 * c0] = val;
                }
            } else {
#pragma unroll
                for (int j = 0; j < 4; ++j) {
                    unsigned k16 = (ksr[ct][j >> 1] >> ((j & 1) * 16)) & 0xFFFFu;
                    unsigned val = k16 | ((unsigned)f2bf(acc[ct][j]) << 16);
                    __builtin_nontemporal_store(
                        val, (unsigned*)&ks[(size_t)(rbase + j) * 256 + 2 * c0]);
                }
            }
        }
    }
}

// One node's aggregation + fused BN/ReLU/L2norm/skipsum epilogue (one wave).
__device__ __forceinline__ void agg_node(
    int node, int lane, int l, int final_norm,
    const ushort_t* __restrict__ ks, const ushort_t* __restrict__ gat,
    const int* __restrict__ row_ptr, const int* __restrict__ csr_src,
    float gx, float gy, float btx, float bty,
    const float* __restrict__ hin_f32, ushort_t* __restrict__ xb,
    float* __restrict__ out_f32) {
    int d0 = lane * 2;
    const ushort_t* ksp = ks + ((unsigned)node << 8);
    u32x2 ksw = __builtin_nontemporal_load((const u32x2*)&ksp[4 * lane]);
    float kx = __uint_as_float(ksw.x << 16);
    float ax = __uint_as_float(ksw.x & 0xFFFF0000u);
    float ky = __uint_as_float(ksw.y << 16);
    float ay = __uint_as_float(ksw.y & 0xFFFF0000u);

    const char* gbase = (const char*)gat;
    const unsigned qvoff = 8u * (unsigned)lane;
    int s = row_ptr[node];
    int e = row_ptr[node + 1];
    int idx = s;

#define GATE(wrd, KK, AA)                                                     \
    do {                                                                      \
        float qf = __uint_as_float((wrd) << 16);                              \
        float vf = __uint_as_float((wrd) & 0xFFFF0000u);                      \
        float g = __builtin_amdgcn_rcpf(1.0f +                                \
                    __builtin_amdgcn_exp2f(KK + qf));                         \
        AA = fmaf(g, vf, AA);                                                 \
    } while (0)

    while (idx + 8 <= e) {
        u32x2 wv[8];
#pragma unroll
        for (int u = 0; u < 8; ++u) {
            unsigned b = (unsigned)csr_src[idx + u];
            wv[u] = *(const u32x2*)(gbase + b + qvoff);
        }
#pragma unroll
        for (int u = 0; u < 8; ++u) {
            GATE(wv[u].x, kx, ax);
            GATE(wv[u].y, ky, ay);
        }
        idx += 8;
    }
    while (idx + 2 <= e) {
        unsigned b0 = (unsigned)csr_src[idx];
        unsigned b1 = (unsigned)csr_src[idx + 1];
        u32x2 w0 = *(const u32x2*)(gbase + b0 + qvoff);
        u32x2 w1 = *(const u32x2*)(gbase + b1 + qvoff);
        GATE(w0.x, kx, ax);
        GATE(w0.y, ky, ay);
        GATE(w1.x, kx, ax);
        GATE(w1.y, ky, ay);
        idx += 2;
    }
    if (idx < e) {
        unsigned b0 = (unsigned)csr_src[idx];
        u32x2 w0 = *(const u32x2*)(gbase + b0 + qvoff);
        GATE(w0.x, kx, ax);
        GATE(w0.y, ky, ay);
    }
#undef GATE

    float rx = fmaxf(ax * gx + btx, 0.f);
    float ry = fmaxf(ay * gy + bty, 0.f);

    float ss = rx * rx + ry * ry;
#pragma unroll
    for (int m = 1; m < 64; m <<= 1) ss += __shfl_xor(ss, m);
    float inv = __builtin_amdgcn_rcpf(fmaxf(sqrtf(ss), 1e-12f));

    float hx, hy;
    if (hin_f32) {
        f32x2 xi = *(const f32x2*)&hin_f32[(size_t)node * DD + d0];
        hx = xi.x + rx * inv;
        hy = xi.y + ry * inv;
    } else {
        unsigned xw = *(const unsigned*)&xb[((unsigned)node << 7) + d0];
        hx = __uint_as_float(xw << 16) + rx * inv;
        hy = __uint_as_float(xw & 0xFFFF0000u) + ry * inv;
    }

    if (final_norm) {
        float s2 = hx * hx + hy * hy;
#pragma unroll
        for (int m = 1; m < 64; m <<= 1) s2 += __shfl_xor(s2, m);
        float inv2 = __builtin_amdgcn_rcpf(fmaxf(sqrtf(s2), 1e-12f));
        f32x2 o;
        o.x = hx * inv2;
        o.y = hy * inv2;
        __builtin_nontemporal_store(o, (f32x2*)&out_f32[(size_t)node * DD + d0]);
    } else {
        unsigned ob = (unsigned)f2bf(hx) | ((unsigned)f2bf(hy) << 16);
        *(unsigned*)&xb[((unsigned)node << 7) + d0] = ob;
    }
}

// ---------------------------------------------------------------------------
// Cooperative megakernel: all phases, grid.sync between them.
// ---------------------------------------------------------------------------
__global__ __launch_bounds__(256, 4) void mega_kernel(
    const int* __restrict__ ei, const float* __restrict__ x,
    const float* __restrict__ Wk, const float* __restrict__ bk,
    const float* __restrict__ Wq, const float* __restrict__ bq,
    const float* __restrict__ Wv, const float* __restrict__ bv,
    const float* __restrict__ Ws,
    const float* __restrict__ gamma, const float* __restrict__ beta,
    float* __restrict__ out,
    ushort_t* __restrict__ ks, ushort_t* __restrict__ gat, ushort_t* __restrict__ xb,
    ushort_t* __restrict__ wall,
    int* __restrict__ srcs, int* __restrict__ dsts, int* __restrict__ count,
    int* __restrict__ cursor, int* __restrict__ row_ptr, int* __restrict__ csr_src,
    int* __restrict__ blocksum, int* __restrict__ blockoff) {
    cg::grid_group grid = cg::this_grid();
    __shared__ ushort_t wlds[DD * DD];   // 32 KB; reused as int tmp in scans
    int* tmp = (int*)wlds;

    const int tid = threadIdx.x;
    const int bid = blockIdx.x;
    const int gth = bid * 256 + tid;
    const int w = tid >> 6;
    const int lane = tid & 63;

    // P0: zero count + convert weights to bf16
    for (int i = gth; i < NN; i += GSTRIDE) count[i] = 0;
    for (int g = gth; g < NWG; g += GSTRIDE) cvt_w_gran(g, Wk, Wq, Wv, Ws, wall);
    grid.sync();

    // P1: edge convert + degree histogram
    {
        bool is64 = detect64(ei);
        for (int e = gth; e < NE; e += GSTRIDE) conv_edge(e, is64, ei, srcs, dsts, count);
    }
    grid.sync();

    // P2: scan1 (block-local exclusive scans)
    if (bid < SCAN_NBLK) {
        int i = bid * 256 + tid;
        int v = (i < NN) ? count[i] : 0;
        tmp[tid] = v;
        __syncthreads();
        for (int off = 1; off < 256; off <<= 1) {
            int u = (tid >= off) ? tmp[tid - off] : 0;
            __syncthreads();
            tmp[tid] += u;
            __syncthreads();
        }
        if (i < NN) row_ptr[i] = tmp[tid] - v;
        if (tid == 255) blocksum[bid] = tmp[255];
    }
    grid.sync();

    // P3: scan2 (block 0 scans the 157 block sums)
    if (bid == 0) {
        int v = (tid < SCAN_NBLK) ? blocksum[tid] : 0;
        tmp[tid] = v;
        __syncthreads();
        for (int off = 1; off < 256; off <<= 1) {
            int u = (tid >= off) ? tmp[tid - off] : 0;
            __syncthreads();
            tmp[tid] += u;
            __syncthreads();
        }
        if (tid < SCAN_NBLK) blockoff[tid] = tmp[tid] - v;
    }
    grid.sync();

    // P4: scan3 (finalize row_ptr, init cursor)
    for (int i = gth; i < NN; i += GSTRIDE) {
        int r = row_ptr[i] + blockoff[i >> 8];
        row_ptr[i] = r;
        cursor[i] = r;
        if (i == 0) row_ptr[NN] = NE;
    }
    grid.sync();

    // P5: scatter (csr_src holds src*512 byte offsets)
    for (int e = gth; e < NE; e += GSTRIDE) {
        int i = dsts[e];
        int pos = atomicAdd(&cursor[i], 1);
        csr_src[pos] = srcs[e] << 9;
    }
    grid.sync();

    // P6/P7 per layer: GEMM then aggregation
    for (int l = 0; l < NL; ++l) {
        if (bid < NN / 64)
            gemm_tile(bid, l, (l == 0) ? x : nullptr, xb, wall, bk, bq, bv, ks, gat, wlds);
        grid.sync();

        const int d0 = lane * 2;
        float gx = gamma[l * DD + d0], gy = gamma[l * DD + d0 + 1];
        float btx = beta[l * DD + d0], bty = beta[l * DD + d0 + 1];
        int gw = (bid << 2) + w;
        for (int n0 = gw; n0 < NN; n0 += GB * 4) {
            int node = __builtin_amdgcn_readfirstlane(n0);
            agg_node(node, lane, l, (l == NL - 1) ? 1 : 0, ks, gat, row_ptr, csr_src,
                     gx, gy, btx, bty, (l == 0) ? x : nullptr, xb,
                     (l == NL - 1) ? out : nullptr);
        }
        if (l != NL - 1) grid.sync();
    }
}

// ---------------------------------------------------------------------------
// Fallback path (plain launches) — same math via the shared phase bodies
// ---------------------------------------------------------------------------
__global__ void fb_pre_kernel(const int* __restrict__ ei,
                              int* __restrict__ srcs, int* __restrict__ dsts,
                              int* __restrict__ count,
                              const float* __restrict__ Wk, const float* __restrict__ Wq,
                              const float* __restrict__ Wv, const float* __restrict__ Ws,
                              ushort_t* __restrict__ wall) {
    int bid = blockIdx.x;
    if (bid < NB_CONV) {
        bool is64 = detect64(ei);
        int e = bid * 256 + threadIdx.x;
        if (e < NE) conv_edge(e, is64, ei, srcs, dsts, count);
    } else {
        int g = (bid - NB_CONV) * 256 + threadIdx.x;
        if (g < NWG) cvt_w_gran(g, Wk, Wq, Wv, Ws, wall);
    }
}

__global__ __launch_bounds__(256) void fb_scan1(const int* __restrict__ count,
                                                int* __restrict__ row_ptr,
                                                int* __restrict__ blocksum) {
    __shared__ int tmp[256];
    int t = threadIdx.x;
    int i = blockIdx.x * 256 + t;
    int v = (i < NN) ? count[i] : 0;
    tmp[t] = v;
    __syncthreads();
    for (int off = 1; off < 256; off <<= 1) {
        int u = (t >= off) ? tmp[t - off] : 0;
        __syncthreads();
        tmp[t] += u;
        __syncthreads();
    }
    if (i < NN) row_ptr[i] = tmp[t] - v;
    if (t == 255) blocksum[blockIdx.x] = tmp[255];
}

__global__ __launch_bounds__(256) void fb_scan2(const int* __restrict__ blocksum,
                                                int* __restrict__ blockoff) {
    __shared__ int tmp[256];
    int t = threadIdx.x;
    int v = (t < SCAN_NBLK) ? blocksum[t] : 0;
    tmp[t] = v;
    __syncthreads();
    for (int off = 1; off < 256; off <<= 1) {
        int u = (t >= off) ? tmp[t - off] : 0;
        __syncthreads();
        tmp[t] += u;
        __syncthreads();
    }
    if (t < SCAN_NBLK) blockoff[t] = tmp[t] - v;
}

__global__ void fb_scan3(int* __restrict__ row_ptr, const int* __restrict__ blockoff,
                         int* __restrict__ cursor) {
    int i = blockIdx.x * blockDim.x + threadIdx.x;
    if (i >= NN) return;
    int r = row_ptr[i] + blockoff[i >> 8];
    row_ptr[i] = r;
    cursor[i] = r;
    if (i == 0) row_ptr[NN] = NE;
}

__global__ void fb_scatter(const int* __restrict__ srcs, const int* __restrict__ dsts,
                           int* __restrict__ cursor, int* __restrict__ csr_src) {
    int e = blockIdx.x * blockDim.x + threadIdx.x;
    if (e >= NE) return;
    int i = dsts[e];
    int pos = atomicAdd(&cursor[i], 1);
    csr_src[pos] = srcs[e] << 9;
}

__global__ __launch_bounds__(256) void fb_gemm(const ushort_t* __restrict__ xb,
                                               const float* __restrict__ xf,
                                               const ushort_t* __restrict__ wall,
                                               const float* __restrict__ bk,
                                               const float* __restrict__ bq,
                                               const float* __restrict__ bv,
                                               ushort_t* __restrict__ ks,
                                               ushort_t* __restrict__ gat, int layer) {
    __shared__ ushort_t wlds[DD * DD];
    gemm_tile(blockIdx.x, layer, xf, xb, wall, bk, bq, bv, ks, gat, wlds);
}

__global__ __launch_bounds__(256) void fb_agg(const ushort_t* __restrict__ ks,
                                              const ushort_t* __restrict__ gat,
                                              const int* __restrict__ row_ptr,
                                              const int* __restrict__ csr_src,
                                              const float* __restrict__ gamma,
                                              const float* __restrict__ beta,
                                              const float* __restrict__ hin_f32,
                                              ushort_t* __restrict__ xb,
                                              float* __restrict__ out_f32,
                                              int layer, int final_norm) {
    int wid = __builtin_amdgcn_readfirstlane(
        (int)((blockIdx.x * blockDim.x + threadIdx.x) >> 6));
    if (wid >= NN) return;
    int lane = threadIdx.x & 63;
    int d0 = lane * 2;
    float gx = gamma[layer * DD + d0], gy = gamma[layer * DD + d0 + 1];
    float btx = beta[layer * DD + d0], bty = beta[layer * DD + d0 + 1];
    agg_node(wid, lane, layer, final_norm, ks, gat, row_ptr, csr_src,
             gx, gy, btx, bty, hin_f32, xb, out_f32);
}

// ---------------------------------------------------------------------------
extern "C" void kernel_launch(void* const* d_in, const int* in_sizes, int n_in,
                              void* d_out, int out_size, void* d_ws, size_t ws_size,
                              hipStream_t stream) {
    const float* x     = (const float*)d_in[0];
    const int*   ei    = (const int*)d_in[1];
    const float* Wk    = (const float*)d_in[2];
    const float* bk    = (const float*)d_in[3];
    const float* Wq    = (const float*)d_in[4];
    const float* bq    = (const float*)d_in[5];
    const float* Wv    = (const float*)d_in[6];
    const float* bv    = (const float*)d_in[7];
    const float* Ws    = (const float*)d_in[8];
    const float* gamma = (const float*)d_in[9];
    const float* beta  = (const float*)d_in[10];
    float* out = (float*)d_out;

    // workspace layout
    ushort_t* ks  = (ushort_t*)d_ws;                     // [N][256] bf16 (20.5 MB)
    ushort_t* gat = ks + (size_t)NN * 256;               // [N][256] bf16 (20.5 MB)
    ushort_t* xb  = gat + (size_t)NN * 256;              // [N][128] bf16 (10.2 MB)
    ushort_t* wall = xb + (size_t)NN * DD;               // weights bf16 (0.4 MB)
    int* srcs     = (int*)(wall + (size_t)NL * 4 * DD * DD);
    int* dsts     = srcs + NE;
    int* count    = dsts + NE;
    int* cursor   = count + NN;
    int* row_ptr  = cursor + NN;
    int* csr_src  = row_ptr + (NN + 1);
    int* blocksum = csr_src + NE;
    int* blockoff = blocksum + SCAN_NBLK;

    void* kargs[] = {(void*)&ei, (void*)&x, (void*)&Wk, (void*)&bk, (void*)&Wq,
                     (void*)&bq, (void*)&Wv, (void*)&bv, (void*)&Ws, (void*)&gamma,
                     (void*)&beta, (void*)&out, (void*)&ks, (void*)&gat, (void*)&xb,
                     (void*)&wall, (void*)&srcs, (void*)&dsts, (void*)&count,
                     (void*)&cursor, (void*)&row_ptr, (void*)&csr_src,
                     (void*)&blocksum, (void*)&blockoff};

    hipError_t err = hipLaunchCooperativeKernel((void*)mega_kernel, dim3(GB), dim3(256),
                                                kargs, 0, stream);
    if (err != hipSuccess) {
        (void)hipGetLastError();  // clear sticky error, use fallback path
        (void)hipMemsetAsync(count, 0, NN * sizeof(int), stream);
        fb_pre_kernel<<<NB_CONV + (NWG + 255) / 256, 256, 0, stream>>>(
            ei, srcs, dsts, count, Wk, Wq, Wv, Ws, wall);
        fb_scan1<<<SCAN_NBLK, 256, 0, stream>>>(count, row_ptr, blocksum);
        fb_scan2<<<1, 256, 0, stream>>>(blocksum, blockoff);
        fb_scan3<<<(NN + 255) / 256, 256, 0, stream>>>(row_ptr, blockoff, cursor);
        fb_scatter<<<(NE + 255) / 256, 256, 0, stream>>>(srcs, dsts, cursor, csr_src);
        for (int l = 0; l < NL; ++l) {
            fb_gemm<<<NN / 64, 256, 0, stream>>>(xb, (l == 0) ? x : nullptr, wall,
                                                 bk, bq, bv, ks, gat, l);
            fb_agg<<<(NN * 64) / 256, 256, 0, stream>>>(
                ks, gat, row_ptr, csr_src, gamma, beta,
                (l == 0) ? x : nullptr, xb,
                (l == NL - 1) ? out : nullptr, l, (l == NL - 1) ? 1 : 0);
        }
    }
}

// Round 11
// 280.518 us; speedup vs baseline: 5.7726x; 5.7726x over previous
//
#include <hip/hip_runtime.h>
#include <math.h>

#define NN 40000
#define NE 640000
#define DD 128
#define NL 3
#define SCAN_NBLK ((NN + 255) / 256)   // 157
#define NB_CONV ((NE + 255) / 256)     // 2500
#define NB_W    (NL * 4 * DD * DD / 8 / 256)  // 96
#define NEG_LOG2E -1.4426950408889634f

typedef short s16x8 __attribute__((ext_vector_type(8)));
typedef float f32x4 __attribute__((ext_vector_type(4)));
typedef float f32x2 __attribute__((ext_vector_type(2)));
typedef unsigned short ushort_t;

// bf16 <-> f32 via bit ops (RNE)
__device__ __forceinline__ ushort_t f2bf(float f) {
    unsigned int u = __float_as_uint(f);
    u = (u + 0x7FFFu + ((u >> 16) & 1u)) >> 16;
    return (ushort_t)u;
}
__device__ __forceinline__ float bf2f(ushort_t h) {
    return __uint_as_float(((unsigned int)h) << 16);
}

// ---------------------------------------------------------------------------
// Fused edge convert+histogram AND weight bf16 conversion (disjoint blocks)
// ---------------------------------------------------------------------------
__global__ void pre_kernel(const int* __restrict__ ei,
                           int* __restrict__ srcs, int* __restrict__ dsts,
                           int* __restrict__ count,
                           const float* __restrict__ Wk, const float* __restrict__ Wq,
                           const float* __restrict__ Wv, const float* __restrict__ Ws,
                           ushort_t* __restrict__ wall) {
    int bid = blockIdx.x;
    if (bid < NB_CONV) {
        __shared__ int sh_is64;
        if (threadIdx.x == 0) {
            int is64 = 1;
            for (int k = 0; k < 32; ++k)
                if (ei[2 * k + 1] != 0) { is64 = 0; break; }
            sh_is64 = is64;
        }
        __syncthreads();
        int e = bid * 256 + threadIdx.x;
        if (e >= NE) return;
        int s, d;
        if (sh_is64) {
            s = ei[2 * e];
            d = ei[2 * (NE + e)];
        } else {
            s = ei[e];
            d = ei[NE + e];
        }
        srcs[e] = s;
        dsts[e] = d;
        atomicAdd(&count[d], 1);
    } else {
        int g = (bid - NB_CONV) * 256 + threadIdx.x;
        size_t flat = (size_t)g * 8;
        int l = (int)(flat / (4 * DD * DD));
        int r = (int)(flat % (4 * DD * DD));
        int m = r / (DD * DD);
        int o = r % (DD * DD);
        const float* src;
        switch (m) {
            case 0: src = Wk; break;
            case 1: src = Wq; break;
            case 2: src = Wv; break;
            default: src = Ws; break;
        }
        const float* p = src + (size_t)l * DD * DD + o;
        s16x8 ov;
#pragma unroll
        for (int j = 0; j < 8; ++j) ov[j] = (short)f2bf(p[j]);
        *(s16x8*)&wall[flat] = ov;
    }
}

__global__ __launch_bounds__(256) void scan1_kernel(const int* __restrict__ count,
                                                    int* __restrict__ row_ptr,
                                                    int* __restrict__ blocksum) {
    __shared__ int tmp[256];
    int t = threadIdx.x;
    int i = blockIdx.x * 256 + t;
    int v = (i < NN) ? count[i] : 0;
    tmp[t] = v;
    __syncthreads();
    for (int off = 1; off < 256; off <<= 1) {
        int u = (t >= off) ? tmp[t - off] : 0;
        __syncthreads();
        tmp[t] += u;
        __syncthreads();
    }
    if (i < NN) row_ptr[i] = tmp[t] - v;
    if (t == 255) blocksum[blockIdx.x] = tmp[255];
}

__global__ __launch_bounds__(256) void scan2_kernel(const int* __restrict__ blocksum,
                                                    int* __restrict__ blockoff) {
    __shared__ int tmp[256];
    int t = threadIdx.x;
    int v = (t < SCAN_NBLK) ? blocksum[t] : 0;
    tmp[t] = v;
    __syncthreads();
    for (int off = 1; off < 256; off <<= 1) {
        int u = (t >= off) ? tmp[t - off] : 0;
        __syncthreads();
        tmp[t] += u;
        __syncthreads();
    }
    if (t < SCAN_NBLK) blockoff[t] = tmp[t] - v;
}

__global__ void scan3_kernel(int* __restrict__ row_ptr, const int* __restrict__ blockoff,
                             int* __restrict__ cursor) {
    int i = blockIdx.x * blockDim.x + threadIdx.x;
    if (i >= NN) return;
    int r = row_ptr[i] + blockoff[i >> 8];
    row_ptr[i] = r;
    cursor[i] = r;
    if (i == 0) row_ptr[NN] = NE;
}

// csr_src holds src*512 (byte offset of the gather record in gat)
__global__ void scatter_kernel(const int* __restrict__ srcs, const int* __restrict__ dsts,
                               int* __restrict__ cursor, int* __restrict__ csr_src) {
    int e = blockIdx.x * blockDim.x + threadIdx.x;
    if (e >= NE) return;
    int i = dsts[e];
    int pos = atomicAdd(&cursor[i], 1);
    csr_src[pos] = srcs[e] << 9;
}

// ---------------------------------------------------------------------------
// MFMA 4-way GEMM. Input: xb bf16, or xf f32 (layer 0, converted on load).
// Outputs:
//   ks  plane [N][256] ushort: k' = -log2e*(k+bk) | s   (nontemporal)
//   gat plane [N][256] ushort: q',v interleaved         (hot gather table)
// ---------------------------------------------------------------------------
__global__ __launch_bounds__(256) void gemm4_mfma(
    const ushort_t* __restrict__ xb,
    const float* __restrict__ xf,        // non-null on layer 0
    const ushort_t* __restrict__ wall,
    const float* __restrict__ bk, const float* __restrict__ bq,
    const float* __restrict__ bv,
    ushort_t* __restrict__ ks, ushort_t* __restrict__ gat,
    int layer) {
    __shared__ ushort_t wlds[DD * DD];

    const int t = threadIdx.x;
    const int w = t >> 6;
    const int lane = t & 63;
    const int row0 = blockIdx.x * 64;

    const int arow = row0 + w * 16 + (lane & 15);
    s16x8 afrag[4];
    if (xf) {
        const float* apf = xf + (size_t)arow * DD + ((lane >> 4) << 3);
#pragma unroll
        for (int kb = 0; kb < 4; ++kb) {
            f32x4 lo = *(const f32x4*)(apf + kb * 32);
            f32x4 hi = *(const f32x4*)(apf + kb * 32 + 4);
#pragma unroll
            for (int j = 0; j < 4; ++j) {
                afrag[kb][j] = (short)f2bf(lo[j]);
                afrag[kb][j + 4] = (short)f2bf(hi[j]);
            }
        }
    } else {
        const ushort_t* ap = xb + (size_t)arow * DD + ((lane >> 4) << 3);
#pragma unroll
        for (int kb = 0; kb < 4; ++kb) afrag[kb] = *(const s16x8*)(ap + kb * 32);
    }

    const int dlow = lane & 15;
    const int dbase = dlow * 256;
    const int swz = (lane & 7) << 4;
    const int g16 = (lane >> 4) << 4;

    unsigned int qs[8][2];  // saved bf16 q' (packed pairs), m==1 -> m==2

    for (int m = 0; m < 4; ++m) {
        if (m) __syncthreads();
        const ushort_t* wsrc = wall + (((size_t)layer * 4 + m) << 14);
#pragma unroll
        for (int p = 0; p < 8; ++p) {
            int g = p * 256 + t;
            int d = g >> 4;
            int s = g & 15;
            int byteoff = d * 256 + ((s * 16) ^ ((d & 7) << 4));
            *(s16x8*)((char*)wlds + byteoff) = *(const s16x8*)(wsrc + (size_t)g * 8);
        }
        __syncthreads();

        f32x4 acc[8];
#pragma unroll
        for (int ct = 0; ct < 8; ++ct) acc[ct] = (f32x4){0.f, 0.f, 0.f, 0.f};

#pragma unroll
        for (int kb = 0; kb < 4; ++kb) {
#pragma unroll
            for (int ct = 0; ct < 8; ++ct) {
                s16x8 bfrag = *(const s16x8*)((char*)wlds + ct * 4096 + dbase +
                                              ((kb * 64 + g16) ^ swz));
                acc[ct] = __builtin_amdgcn_mfma_f32_16x16x32_bf16(afrag[kb], bfrag,
                                                                  acc[ct], 0, 0, 0);
            }
        }

        const int rbase = row0 + w * 16 + ((lane >> 4) << 2);
#pragma unroll
        for (int ct = 0; ct < 8; ++ct) {
            int c0 = ct * 16 + dlow;
            if (m == 0) {
                float bval = bk[layer * DD + c0];
#pragma unroll
                for (int j = 0; j < 4; ++j)
                    __builtin_nontemporal_store(
                        f2bf((acc[ct][j] + bval) * NEG_LOG2E),
                        &ks[(size_t)(rbase + j) * 256 + c0]);
            } else if (m == 1) {
                float bval = bq[layer * DD + c0];
                qs[ct][0] = (unsigned int)f2bf((acc[ct][0] + bval) * NEG_LOG2E) |
                            ((unsigned int)f2bf((acc[ct][1] + bval) * NEG_LOG2E) << 16);
                qs[ct][1] = (unsigned int)f2bf((acc[ct][2] + bval) * NEG_LOG2E) |
                            ((unsigned int)f2bf((acc[ct][3] + bval) * NEG_LOG2E) << 16);
            } else if (m == 2) {
                float bval = bv[layer * DD + c0];
#pragma unroll
                for (int j = 0; j < 4; ++j) {
                    unsigned int q16 = (qs[ct][j >> 1] >> ((j & 1) * 16)) & 0xFFFFu;
                    unsigned int val = q16 | ((unsigned int)f2bf(acc[ct][j] + bval) << 16);
                    *(unsigned int*)&gat[(size_t)(rbase + j) * 256 + 2 * c0] = val;
                }
            } else {
#pragma unroll
                for (int j = 0; j < 4; ++j)
                    __builtin_nontemporal_store(
                        f2bf(acc[ct][j]),
                        &ks[(size_t)(rbase + j) * 256 + 128 + c0]);
            }
        }
    }
}

// ---------------------------------------------------------------------------
// Aggregation + fused epilogue. One wave per node; lane owns dims 2l,2l+1.
// 8-deep gather unroll (best measured, R8). Residual input from f32 x on
// layer 0, else bf16 xb (in place). Final layer writes f32 out.
// ---------------------------------------------------------------------------
__global__ __launch_bounds__(256) void agg_kernel(
    const ushort_t* __restrict__ ks,    // [N][256] bf16: k' | s
    const ushort_t* __restrict__ gat,   // [N][256] bf16: q'v interleaved
    const int* __restrict__ row_ptr,
    const int* __restrict__ csr_src,    // pre-scaled src*512 (byte offsets)
    const float* __restrict__ gamma, const float* __restrict__ beta,
    const float* __restrict__ hin_f32,  // non-null on layer 0 (residual = x)
    ushort_t* __restrict__ xb,          // [N][128] bf16 h (read/write in place)
    float* __restrict__ out_f32,        // non-null on final layer
    int layer, int final_norm) {
    int wid = __builtin_amdgcn_readfirstlane(
        (int)((blockIdx.x * blockDim.x + threadIdx.x) >> 6));
    if (wid >= NN) return;
    int lane = threadIdx.x & 63;
    int d0 = lane * 2;

    const ushort_t* ksp = ks + ((unsigned)wid << 8);
    unsigned kword = __builtin_nontemporal_load((const unsigned*)&ksp[d0]);
    unsigned sword = __builtin_nontemporal_load((const unsigned*)&ksp[128 + d0]);
    float kx = __uint_as_float(kword << 16);
    float ky = __uint_as_float(kword & 0xFFFF0000u);
    float ax = __uint_as_float(sword << 16);
    float ay = __uint_as_float(sword & 0xFFFF0000u);

    const char* gbase = (const char*)gat;
    const unsigned qvoff = 8u * (unsigned)lane;   // byte offset within record
    int s = row_ptr[wid];
    int e = row_ptr[wid + 1];
    int idx = s;

#define GATE(wrd, KK, AA)                                                     \
    do {                                                                      \
        float qf = __uint_as_float((wrd) << 16);                              \
        float vf = __uint_as_float((wrd) & 0xFFFF0000u);                      \
        float g = __builtin_amdgcn_rcpf(1.0f +                                \
                    __builtin_amdgcn_exp2f(KK + qf));                         \
        AA = fmaf(g, vf, AA);                                                 \
    } while (0)

    while (idx + 8 <= e) {
        uint2 wv[8];
#pragma unroll
        for (int u = 0; u < 8; ++u) {
            unsigned b = (unsigned)csr_src[idx + u];
            wv[u] = *(const uint2*)(gbase + b + qvoff);
        }
#pragma unroll
        for (int u = 0; u < 8; ++u) {
            GATE(wv[u].x, kx, ax);
            GATE(wv[u].y, ky, ay);
        }
        idx += 8;
    }
    while (idx + 2 <= e) {
        unsigned b0 = (unsigned)csr_src[idx];
        unsigned b1 = (unsigned)csr_src[idx + 1];
        uint2 w0 = *(const uint2*)(gbase + b0 + qvoff);
        uint2 w1 = *(const uint2*)(gbase + b1 + qvoff);
        GATE(w0.x, kx, ax);
        GATE(w0.y, ky, ay);
        GATE(w1.x, kx, ax);
        GATE(w1.y, ky, ay);
        idx += 2;
    }
    if (idx < e) {
        unsigned b0 = (unsigned)csr_src[idx];
        uint2 w0 = *(const uint2*)(gbase + b0 + qvoff);
        GATE(w0.x, kx, ax);
        GATE(w0.y, ky, ay);
    }
#undef GATE

    float gx = gamma[layer * DD + d0], gy = gamma[layer * DD + d0 + 1];
    float btx = beta[layer * DD + d0], bty = beta[layer * DD + d0 + 1];
    float rx = fmaxf(ax * gx + btx, 0.f);
    float ry = fmaxf(ay * gy + bty, 0.f);

    float ss = rx * rx + ry * ry;
#pragma unroll
    for (int m = 1; m < 64; m <<= 1) ss += __shfl_xor(ss, m);
    float inv = __builtin_amdgcn_rcpf(fmaxf(sqrtf(ss), 1e-12f));

    float hx, hy;
    if (hin_f32) {
        f32x2 xi = *(const f32x2*)&hin_f32[(size_t)wid * DD + d0];
        hx = xi.x + rx * inv;
        hy = xi.y + ry * inv;
    } else {
        unsigned xw = *(const unsigned*)&xb[((unsigned)wid << 7) + d0];
        hx = __uint_as_float(xw << 16) + rx * inv;
        hy = __uint_as_float(xw & 0xFFFF0000u) + ry * inv;
    }

    if (final_norm) {
        float s2 = hx * hx + hy * hy;
#pragma unroll
        for (int m = 1; m < 64; m <<= 1) s2 += __shfl_xor(s2, m);
        float inv2 = __builtin_amdgcn_rcpf(fmaxf(sqrtf(s2), 1e-12f));
        f32x2 o;
        o.x = hx * inv2;
        o.y = hy * inv2;
        __builtin_nontemporal_store(o, (f32x2*)&out_f32[(size_t)wid * DD + d0]);
    } else {
        unsigned ob = (unsigned)f2bf(hx) | ((unsigned)f2bf(hy) << 16);
        *(unsigned*)&xb[((unsigned)wid << 7) + d0] = ob;
    }
}

// ---------------------------------------------------------------------------
extern "C" void kernel_launch(void* const* d_in, const int* in_sizes, int n_in,
                              void* d_out, int out_size, void* d_ws, size_t ws_size,
                              hipStream_t stream) {
    const float* x     = (const float*)d_in[0];
    const int*   ei    = (const int*)d_in[1];
    const float* Wk    = (const float*)d_in[2];
    const float* bk    = (const float*)d_in[3];
    const float* Wq    = (const float*)d_in[4];
    const float* bq    = (const float*)d_in[5];
    const float* Wv    = (const float*)d_in[6];
    const float* bv    = (const float*)d_in[7];
    const float* Ws    = (const float*)d_in[8];
    const float* gamma = (const float*)d_in[9];
    const float* beta  = (const float*)d_in[10];
    float* out = (float*)d_out;

    // workspace layout
    ushort_t* ks  = (ushort_t*)d_ws;                     // [N][256] bf16 (20.5 MB)
    ushort_t* gat = ks + (size_t)NN * 256;               // [N][256] bf16 (20.5 MB)
    ushort_t* xb  = gat + (size_t)NN * 256;              // [N][128] bf16 (10.2 MB)
    ushort_t* wall = xb + (size_t)NN * DD;               // weights bf16 (0.4 MB)
    int* srcs     = (int*)(wall + (size_t)NL * 4 * DD * DD);
    int* dsts     = srcs + NE;
    int* count    = dsts + NE;
    int* cursor   = count + NN;
    int* row_ptr  = cursor + NN;
    int* csr_src  = row_ptr + (NN + 1);
    int* blocksum = csr_src + NE;
    int* blockoff = blocksum + SCAN_NBLK;

    (void)hipMemsetAsync(count, 0, NN * sizeof(int), stream);
    pre_kernel<<<NB_CONV + NB_W, 256, 0, stream>>>(ei, srcs, dsts, count,
                                                   Wk, Wq, Wv, Ws, wall);
    scan1_kernel<<<SCAN_NBLK, 256, 0, stream>>>(count, row_ptr, blocksum);
    scan2_kernel<<<1, 256, 0, stream>>>(blocksum, blockoff);
    scan3_kernel<<<(NN + 255) / 256, 256, 0, stream>>>(row_ptr, blockoff, cursor);
    scatter_kernel<<<(NE + 255) / 256, 256, 0, stream>>>(srcs, dsts, cursor, csr_src);

    for (int l = 0; l < NL; ++l) {
        gemm4_mfma<<<NN / 64, 256, 0, stream>>>(xb, (l == 0) ? x : nullptr, wall,
                                                bk, bq, bv, ks, gat, l);
        agg_kernel<<<(NN * 64) / 256, 256, 0, stream>>>(
            ks, gat, row_ptr, csr_src, gamma, beta,
            (l == 0) ? x : nullptr, xb,
            (l == NL - 1) ? out : nullptr, l, (l == NL - 1) ? 1 : 0);
    }
}